// Round 4
// baseline (458.706 us; speedup 1.0000x reference)
//
#include <hip/hip_runtime.h>
#include <hip/hip_bf16.h>
#include <math.h>

#define T_DIM 2048
#define K_DIM 17
#define HID   64
#define B_DIM 32
#define TT    8                       // output t's per workgroup

typedef short s16x8 __attribute__((ext_vector_type(8)));
typedef float f32x4 __attribute__((ext_vector_type(4)));

__device__ __forceinline__ float bf2f(short u) {
    unsigned v = ((unsigned)(unsigned short)u) << 16;
    return __builtin_bit_cast(float, v);
}
__device__ __forceinline__ short f2bf(float f) {
    __hip_bfloat16 h = __float2bfloat16(f);
    return __builtin_bit_cast(short, h);
}

// COCO skeleton sparsity: column-v nonzeros of adj (incl. self).
__device__ const int d_NBR_PTR[18] = {0,3,6,9,11,13,17,21,24,27,29,31,34,37,40,43,45,47};
__device__ const int d_NBR_K[47] = {
    0,1,2,  0,1,3,  0,2,4,  1,3,  2,4,
    5,6,7,11,  5,6,8,12,  5,7,9,  6,8,10,  7,9,  8,10,
    5,11,13,  6,12,14,  11,13,15,  12,14,16,  13,15,  14,16 };
static constexpr int NBR_PTR[18] = {0,3,6,9,11,13,17,21,24,27,29,31,34,37,40,43,45,47};
static constexpr int NBR_K[47] = {
    0,1,2,  0,1,3,  0,2,4,  1,3,  2,4,
    5,6,7,11,  5,6,8,12,  5,7,9,  6,8,10,  7,9,  8,10,
    5,11,13,  6,12,14,  11,13,15,  12,14,16,  13,15,  14,16 };

// ---------------------------------------------------------------------------
// Fold GCN channel-mix into temporal conv weights (all bf16 B-operands).
//   effT0[o][k32]   k = dt*8+cin (cin<3, dt<3), rest 0   (block1, K=32 MFMA)
//   effT1/2[o][dt*64+c]                                   (blocks 2,3, K=192)
//   bnc[blk*64+o] = s/sqrt(v+eps);  bnc[192+blk*64+o] = b - m*inv
// ---------------------------------------------------------------------------
__global__ void fold_weights_kernel(
    const float* __restrict__ gw0, const float* __restrict__ gw1,
    const float* __restrict__ gw2, const float* __restrict__ tcn,
    const float* __restrict__ bns, const float* __restrict__ bnb,
    const float* __restrict__ bnm, const float* __restrict__ bnv,
    short* __restrict__ effT0, short* __restrict__ effT12,
    float* __restrict__ bnc)
{
    int tid = blockIdx.x * blockDim.x + threadIdx.x;
    int stride = gridDim.x * blockDim.x;
    for (int idx = tid; idx < 2048; idx += stride) {
        int o = idx >> 5, k = idx & 31, dt = k >> 3, cin = k & 7;
        float s = 0.f;
        if (dt < 3 && cin < 3)
            for (int m = 0; m < 64; m++)
                s += gw0[cin * 64 + m] * tcn[(o * 64 + m) * 3 + dt];
        effT0[idx] = f2bf(s);
    }
    for (int idx = tid; idx < 24576; idx += stride) {
        int blk = idx / 12288;
        int r = idx - blk * 12288;
        int o = r / 192, k = r - o * 192, dt = k >> 6, c = k & 63;
        const float* gw = blk ? gw2 : gw1;
        const float* tw = tcn + (size_t)(blk + 1) * 64 * 64 * 3;
        float s = 0.f;
        for (int m = 0; m < 64; m++)
            s += gw[c * 64 + m] * tw[(o * 64 + m) * 3 + dt];
        effT12[idx] = f2bf(s);
    }
    for (int i = tid; i < 192; i += stride) {
        float inv = bns[i] * rsqrtf(bnv[i] + 1e-5f);
        bnc[i] = inv;
        bnc[192 + i] = bnb[i] - bnm[i] * inv;
    }
}

// ---------------------------------------------------------------------------
// Fully fused ST-GCN: all 3 blocks + pool in one kernel.
// WG = (b, 8 output t's).  Slot u = t - (t0-4).
//   A':    gc1(x) -> xg1st rows (s2,j), K=32 layout      [aliases xgA]
//   GEMM1: block1 conv (K=32 MFMA) + BN/ReLU -> yb slots 1..14 (y1)
//   gc2:   graph conv y1 -> xgA[s2]  (xg2, s2 in [0,14))
//   GEMM2: block2 (K=192) + BN/ReLU + residual; y2 -> yb slots 2..13
//   gc3:   graph conv y2 -> xgA[s3]  (xg3, s3 in [0,12))
//   GEMM3: block3 (K=192, DIL=2) + BN/ReLU + residual + pool -> part
// ---------------------------------------------------------------------------
__global__ __launch_bounds__(256) void stgcn_fused_kernel(
    const float* __restrict__ x, const float* __restrict__ adj,
    const short* __restrict__ effT0, const short* __restrict__ effT12,
    const float* __restrict__ bnc, float* __restrict__ part)
{
    __shared__ float adj_s[289];
    __shared__ __align__(16) short yb[16 * 17 * 72];    // 39168 B
    __shared__ __align__(16) short xgA[14 * 17 * 72];   // 34272 B
    __shared__ float pr[4][64];

    short* xg1st = xgA;   // alias: rows [238][40], dead after GEMM1

    const int tid = threadIdx.x;
    const int b = blockIdx.y;
    const int t0 = blockIdx.x * TT;

    const int lane = tid & 63;
    const int wave = tid >> 6;
    const int col = lane & 15;
    const int kgrp = lane >> 4;

    for (int i = tid; i < 289; i += 256) adj_s[i] = adj[i];

    // B-fragments for GEMM1 (K=32): load before barrier (global, independent)
    s16x8 bf1[4];
    #pragma unroll
    for (int nt = 0; nt < 4; nt++)
        bf1[nt] = *(const s16x8*)(effT0 + (nt * 16 + col) * 32 + kgrp * 8);

    __syncthreads();

    // ---- phase A': per-row gc1 + K=32 A-layout pack ----
    if (tid < 238) {
        int s2 = tid / 17, j = tid - s2 * 17;
        float accv[9];
        #pragma unroll
        for (int q = 0; q < 9; q++) accv[q] = 0.f;
        int p0 = d_NBR_PTR[j], p1 = d_NBR_PTR[j + 1];
        #pragma unroll
        for (int dt = 0; dt < 3; dt++) {
            int t = t0 - 4 + s2 + dt;
            if (t >= 0 && t < T_DIM) {
                const float* xp = x + ((size_t)(b * T_DIM + t) * K_DIM) * 3;
                for (int e = p0; e < p1; e++) {
                    int k = d_NBR_K[e];
                    float w = adj_s[k * 17 + j];
                    accv[dt * 3 + 0] += w * xp[k * 3 + 0];
                    accv[dt * 3 + 1] += w * xp[k * 3 + 1];
                    accv[dt * 3 + 2] += w * xp[k * 3 + 2];
                }
            }
        }
        short outv[32];
        #pragma unroll
        for (int q = 0; q < 32; q++) outv[q] = 0;
        #pragma unroll
        for (int dt = 0; dt < 3; dt++)
            #pragma unroll
            for (int cin = 0; cin < 3; cin++)
                outv[dt * 8 + cin] = f2bf(accv[dt * 3 + cin]);
        #pragma unroll
        for (int q = 0; q < 4; q++)
            *(s16x8*)&xg1st[tid * 40 + q * 8] = *(const s16x8*)&outv[q * 8];
    }
    __syncthreads();

    // ---- GEMM1: block1, M=238 (14 t x 17 j), K=32, N=64 ----
    {
        float inv1[4], sh1[4];
        #pragma unroll
        for (int nt = 0; nt < 4; nt++) {
            inv1[nt] = bnc[nt * 16 + col];
            sh1[nt]  = bnc[192 + nt * 16 + col];
        }
        for (int tile = wave; tile < 15; tile += 4) {
            int m = tile * 16 + col;
            int me = m < 237 ? m : 237;
            int s2 = me / 17, j = me - s2 * 17;
            s16x8 a = *(const s16x8*)&xg1st[(s2 * 17 + j) * 40 + kgrp * 8];
            f32x4 acc[4];
            #pragma unroll
            for (int nt = 0; nt < 4; nt++)
                acc[nt] = __builtin_amdgcn_mfma_f32_16x16x32_bf16(
                    a, bf1[nt], (f32x4){0.f, 0.f, 0.f, 0.f}, 0, 0, 0);
            int rl0 = tile * 16 + kgrp * 4;
            int sE = rl0 / 17, vE = rl0 - sE * 17;
            #pragma unroll
            for (int reg = 0; reg < 4; reg++) {
                int m2 = rl0 + reg;
                if (m2 < 238) {
                    int t = t0 - 3 + sE;
                    bool valid = (t >= 0) && (t < T_DIM);
                    #pragma unroll
                    for (int nt = 0; nt < 4; nt++) {
                        float val = valid
                            ? fmaxf(acc[nt][reg] * inv1[nt] + sh1[nt], 0.f) : 0.f;
                        yb[((sE + 1) * 17 + vE) * 72 + nt * 16 + col] = f2bf(val);
                    }
                }
                vE++; if (vE == 17) { vE = 0; sE++; }
            }
        }
    }
    __syncthreads();

    // ---- gc2: y1 -> xg2 ----
    for (int it = tid; it < 14 * 32; it += 256) {
        int s2 = it >> 5, cp = it & 31;
        float y0[17], y1r[17];
        #pragma unroll
        for (int k = 0; k < 17; k++) {
            short2 u = *(const short2*)&yb[((s2 + 1) * 17 + k) * 72 + cp * 2];
            y0[k] = bf2f(u.x); y1r[k] = bf2f(u.y);
        }
        #pragma unroll
        for (int v = 0; v < 17; v++) {
            float g0 = 0.f, g1 = 0.f;
            #pragma unroll
            for (int e = NBR_PTR[v]; e < NBR_PTR[v + 1]; e++) {
                int k = NBR_K[e];
                float w = adj_s[k * 17 + v];
                g0 += w * y0[k]; g1 += w * y1r[k];
            }
            short2 st; st.x = f2bf(g0); st.y = f2bf(g1);
            *(short2*)&xgA[(s2 * 17 + v) * 72 + cp * 2] = st;
        }
    }
    __syncthreads();

    // ---- GEMM2: block2, M=204 (12 t x 17 v), K=192, DIL=1 ----
    {
        s16x8 bf2[6][4];
        #pragma unroll
        for (int kk = 0; kk < 6; kk++)
            #pragma unroll
            for (int nt = 0; nt < 4; nt++)
                bf2[kk][nt] = *(const s16x8*)(effT12 +
                    (nt * 16 + col) * 192 + kk * 32 + kgrp * 8);
        float inv2[4], sh2[4];
        #pragma unroll
        for (int nt = 0; nt < 4; nt++) {
            inv2[nt] = bnc[64 + nt * 16 + col];
            sh2[nt]  = bnc[256 + nt * 16 + col];
        }
        for (int tile = wave; tile < 13; tile += 4) {
            int m = tile * 16 + col;
            int me = m < 203 ? m : 203;
            int s3 = me / 17, v = me - s3 * 17;
            f32x4 acc[4];
            #pragma unroll
            for (int nt = 0; nt < 4; nt++) acc[nt] = (f32x4){0.f, 0.f, 0.f, 0.f};
            #pragma unroll
            for (int kk = 0; kk < 6; kk++) {
                int s = s3 + (kk >> 1);
                int c0 = (kk & 1) * 32 + kgrp * 8;
                s16x8 a = *(const s16x8*)&xgA[(s * 17 + v) * 72 + c0];
                #pragma unroll
                for (int nt = 0; nt < 4; nt++)
                    acc[nt] = __builtin_amdgcn_mfma_f32_16x16x32_bf16(
                        a, bf2[kk][nt], acc[nt], 0, 0, 0);
            }
            int rl0 = tile * 16 + kgrp * 4;
            int sE = rl0 / 17, vE = rl0 - sE * 17;
            #pragma unroll
            for (int reg = 0; reg < 4; reg++) {
                int m2 = rl0 + reg;
                if (m2 < 204) {
                    int t = t0 - 2 + sE;
                    bool valid = (t >= 0) && (t < T_DIM);
                    #pragma unroll
                    for (int nt = 0; nt < 4; nt++) {
                        int idx = ((sE + 2) * 17 + vE) * 72 + nt * 16 + col;
                        float res = bf2f(yb[idx]);
                        float val = valid
                            ? fmaxf(acc[nt][reg] * inv2[nt] + sh2[nt], 0.f) + res
                            : 0.f;
                        yb[idx] = f2bf(val);   // y2 overwrites y1 (same thread)
                    }
                }
                vE++; if (vE == 17) { vE = 0; sE++; }
            }
        }
    }
    __syncthreads();

    // ---- gc3: y2 -> xg3 ----
    for (int it = tid; it < 12 * 32; it += 256) {
        int s3 = it >> 5, cp = it & 31;
        float y0[17], y1r[17];
        #pragma unroll
        for (int k = 0; k < 17; k++) {
            short2 u = *(const short2*)&yb[((s3 + 2) * 17 + k) * 72 + cp * 2];
            y0[k] = bf2f(u.x); y1r[k] = bf2f(u.y);
        }
        #pragma unroll
        for (int v = 0; v < 17; v++) {
            float g0 = 0.f, g1 = 0.f;
            #pragma unroll
            for (int e = NBR_PTR[v]; e < NBR_PTR[v + 1]; e++) {
                int k = NBR_K[e];
                float w = adj_s[k * 17 + v];
                g0 += w * y0[k]; g1 += w * y1r[k];
            }
            short2 st; st.x = f2bf(g0); st.y = f2bf(g1);
            *(short2*)&xgA[(s3 * 17 + v) * 72 + cp * 2] = st;
        }
    }
    __syncthreads();

    // ---- GEMM3: block3, M=136 (8 t x 17 v), K=192, DIL=2, + pool ----
    float psum[4] = {0.f, 0.f, 0.f, 0.f};
    {
        s16x8 bf3[6][4];
        #pragma unroll
        for (int kk = 0; kk < 6; kk++)
            #pragma unroll
            for (int nt = 0; nt < 4; nt++)
                bf3[kk][nt] = *(const s16x8*)(effT12 + 12288 +
                    (nt * 16 + col) * 192 + kk * 32 + kgrp * 8);
        float inv3[4], sh3[4];
        #pragma unroll
        for (int nt = 0; nt < 4; nt++) {
            inv3[nt] = bnc[128 + nt * 16 + col];
            sh3[nt]  = bnc[320 + nt * 16 + col];
        }
        for (int tile = wave; tile < 9; tile += 4) {
            int m = tile * 16 + col;
            int me = m < 135 ? m : 135;
            int s4 = me / 17, v = me - s4 * 17;
            f32x4 acc[4];
            #pragma unroll
            for (int nt = 0; nt < 4; nt++) acc[nt] = (f32x4){0.f, 0.f, 0.f, 0.f};
            #pragma unroll
            for (int kk = 0; kk < 6; kk++) {
                int s = s4 + (kk >> 1) * 2;        // DIL=2
                int c0 = (kk & 1) * 32 + kgrp * 8;
                s16x8 a = *(const s16x8*)&xgA[(s * 17 + v) * 72 + c0];
                #pragma unroll
                for (int nt = 0; nt < 4; nt++)
                    acc[nt] = __builtin_amdgcn_mfma_f32_16x16x32_bf16(
                        a, bf3[kk][nt], acc[nt], 0, 0, 0);
            }
            int rl0 = tile * 16 + kgrp * 4;
            int sE = rl0 / 17, vE = rl0 - sE * 17;
            #pragma unroll
            for (int reg = 0; reg < 4; reg++) {
                int m2 = rl0 + reg;
                if (m2 < 136) {
                    #pragma unroll
                    for (int nt = 0; nt < 4; nt++) {
                        float res = bf2f(yb[((sE + 4) * 17 + vE) * 72 + nt * 16 + col]);
                        psum[nt] += fmaxf(acc[nt][reg] * inv3[nt] + sh3[nt], 0.f) + res;
                    }
                }
                vE++; if (vE == 17) { vE = 0; sE++; }
            }
        }
    }
    // pool reduce
    #pragma unroll
    for (int nt = 0; nt < 4; nt++) {
        float vv = psum[nt];
        vv += __shfl_xor(vv, 16);
        vv += __shfl_xor(vv, 32);
        if (lane < 16) pr[wave][nt * 16 + lane] = vv;
    }
    __syncthreads();
    if (tid < 64)
        part[((size_t)b * 256 + blockIdx.x) * 64 + tid] =
            pr[0][tid] + pr[1][tid] + pr[2][tid] + pr[3][tid];
}

// ---------------------------------------------------------------------------
// Sum 256 partials per (b,c), mean, LayerNorm, FC. 1 wave per b.
// ---------------------------------------------------------------------------
__global__ __launch_bounds__(64) void finish_kernel(
    const float* __restrict__ part, const float* __restrict__ ln_s,
    const float* __restrict__ ln_b, const float* __restrict__ fc_w,
    const float* __restrict__ fc_b, float* __restrict__ out)
{
    const int b = blockIdx.x;
    const int c = threadIdx.x;
    float s = 0.f;
    for (int i = 0; i < 256; i++)
        s += part[((size_t)b * 256 + i) * 64 + c];
    float feat = s / (float)(T_DIM * K_DIM);

    float m = feat;
    #pragma unroll
    for (int off = 32; off > 0; off >>= 1) m += __shfl_down(m, off);
    m = __shfl(m, 0) / 64.f;
    float d = feat - m;
    float v = d * d;
    #pragma unroll
    for (int off = 32; off > 0; off >>= 1) v += __shfl_down(v, off);
    v = __shfl(v, 0) / 64.f;
    float norm = d * rsqrtf(v + 1e-5f) * ln_s[c] + ln_b[c];

    __shared__ float ns[64];
    ns[c] = norm;
    __syncthreads();
    if (c < 10) {
        float o = fc_b[c];
        for (int i = 0; i < 64; i++) o += ns[i] * fc_w[i * 10 + c];
        out[b * 10 + c] = o;
    }
}

// ---------------------------------------------------------------------------
extern "C" void kernel_launch(void* const* d_in, const int* in_sizes, int n_in,
                              void* d_out, int out_size, void* d_ws, size_t ws_size,
                              hipStream_t stream)
{
    const float* kpts = (const float*)d_in[0];
    const float* adj  = (const float*)d_in[1];
    const float* gw0  = (const float*)d_in[2];
    const float* gw1  = (const float*)d_in[3];
    const float* gw2  = (const float*)d_in[4];
    const float* tcn  = (const float*)d_in[5];
    const float* bns  = (const float*)d_in[6];
    const float* bnb  = (const float*)d_in[7];
    const float* bnm  = (const float*)d_in[8];
    const float* bnv  = (const float*)d_in[9];
    const float* lns  = (const float*)d_in[10];
    const float* lnb  = (const float*)d_in[11];
    const float* fcw  = (const float*)d_in[12];
    const float* fcb  = (const float*)d_in[13];
    float* out = (float*)d_out;

    // workspace: bnc(384 f) | part(32*256*64 f) | effT0(2048 bf16) | effT12(24576 bf16)
    float* bnc  = (float*)d_ws;
    float* part = bnc + 384;
    short* effT0  = (short*)(part + (size_t)B_DIM * 256 * 64);
    short* effT12 = effT0 + 2048;
    // total ~2.15 MB — no chunking needed, activations never leave LDS

    fold_weights_kernel<<<64, 256, 0, stream>>>(gw0, gw1, gw2, tcn,
                                                bns, bnb, bnm, bnv,
                                                effT0, effT12, bnc);

    stgcn_fused_kernel<<<dim3(T_DIM / TT, B_DIM), 256, 0, stream>>>(
        kpts, adj, effT0, effT12, bnc, part);

    finish_kernel<<<B_DIM, 64, 0, stream>>>(part, lns, lnb, fcw, fcb, out);
}

// Round 5
// 432.172 us; speedup vs baseline: 1.0614x; 1.0614x over previous
//
#include <hip/hip_runtime.h>
#include <hip/hip_bf16.h>
#include <math.h>

#define T_DIM 2048
#define K_DIM 17
#define HID   64
#define B_DIM 32
#define TT    8                       // output t's per workgroup

typedef short s16x8 __attribute__((ext_vector_type(8)));
typedef float f32x4 __attribute__((ext_vector_type(4)));

__device__ __forceinline__ float bf2f(short u) {
    unsigned v = ((unsigned)(unsigned short)u) << 16;
    return __builtin_bit_cast(float, v);
}
// cold-path precise convert (weights)
__device__ __forceinline__ short f2bf(float f) {
    __hip_bfloat16 h = __float2bfloat16(f);
    return __builtin_bit_cast(short, h);
}
// hot-path: round-half-up bf16, 2 integer ops
__device__ __forceinline__ short f2bf_fast(float f) {
    unsigned u = __builtin_bit_cast(unsigned, f);
    return (short)((u + 0x8000u) >> 16);
}
// pack two floats -> (lo,hi) bf16 pair in one dword
__device__ __forceinline__ unsigned pk2bf(float lo, float hi) {
    unsigned ul = __builtin_bit_cast(unsigned, lo);
    unsigned uh = __builtin_bit_cast(unsigned, hi);
    return ((ul + 0x8000u) >> 16) | ((uh + 0x8000u) & 0xFFFF0000u);
}

// COCO skeleton sparsity: column-v nonzeros of adj (incl. self).
__device__ const int d_NBR_PTR[18] = {0,3,6,9,11,13,17,21,24,27,29,31,34,37,40,43,45,47};
__device__ const int d_NBR_K[47] = {
    0,1,2,  0,1,3,  0,2,4,  1,3,  2,4,
    5,6,7,11,  5,6,8,12,  5,7,9,  6,8,10,  7,9,  8,10,
    5,11,13,  6,12,14,  11,13,15,  12,14,16,  13,15,  14,16 };
static constexpr int NBR_PTR[18] = {0,3,6,9,11,13,17,21,24,27,29,31,34,37,40,43,45,47};
static constexpr int NBR_K[47] = {
    0,1,2,  0,1,3,  0,2,4,  1,3,  2,4,
    5,6,7,11,  5,6,8,12,  5,7,9,  6,8,10,  7,9,  8,10,
    5,11,13,  6,12,14,  11,13,15,  12,14,16,  13,15,  14,16 };

// ---------------------------------------------------------------------------
// Fold GCN channel-mix into temporal conv weights (all bf16 B-operands).
//   effT0[o][k32]   k = dt*8+cin (cin<3, dt<3), rest 0   (block1, K=32 MFMA)
//   effT1/2[o][dt*64+c]                                   (blocks 2,3, K=192)
//   bnc[blk*64+o] = s/sqrt(v+eps);  bnc[192+blk*64+o] = b - m*inv
// ---------------------------------------------------------------------------
__global__ void fold_weights_kernel(
    const float* __restrict__ gw0, const float* __restrict__ gw1,
    const float* __restrict__ gw2, const float* __restrict__ tcn,
    const float* __restrict__ bns, const float* __restrict__ bnb,
    const float* __restrict__ bnm, const float* __restrict__ bnv,
    short* __restrict__ effT0, short* __restrict__ effT12,
    float* __restrict__ bnc)
{
    int tid = blockIdx.x * blockDim.x + threadIdx.x;
    int stride = gridDim.x * blockDim.x;
    for (int idx = tid; idx < 2048; idx += stride) {
        int o = idx >> 5, k = idx & 31, dt = k >> 3, cin = k & 7;
        float s = 0.f;
        if (dt < 3 && cin < 3)
            for (int m = 0; m < 64; m++)
                s += gw0[cin * 64 + m] * tcn[(o * 64 + m) * 3 + dt];
        effT0[idx] = f2bf(s);
    }
    for (int idx = tid; idx < 24576; idx += stride) {
        int blk = idx / 12288;
        int r = idx - blk * 12288;
        int o = r / 192, k = r - o * 192, dt = k >> 6, c = k & 63;
        const float* gw = blk ? gw2 : gw1;
        const float* tw = tcn + (size_t)(blk + 1) * 64 * 64 * 3;
        float s = 0.f;
        for (int m = 0; m < 64; m++)
            s += gw[c * 64 + m] * tw[(o * 64 + m) * 3 + dt];
        effT12[idx] = f2bf(s);
    }
    for (int i = tid; i < 192; i += stride) {
        float inv = bns[i] * rsqrtf(bnv[i] + 1e-5f);
        bnc[i] = inv;
        bnc[192 + i] = bnb[i] - bnm[i] * inv;
    }
}

// ---------------------------------------------------------------------------
// Fully fused ST-GCN: all 3 blocks + pool in one kernel.
// WG = (b, 8 output t's).  Slot u = t - (t0-4).
//   load:  x tile (16 t x 51 f) -> LDS, coalesced
//   A':    gc1(xt) -> xg1st rows (s2,j), K=32 layout      [aliases xgA]
//   GEMM1: block1 conv (K=32 MFMA) + BN/ReLU -> yb slots 1..14 (y1)
//   gc2:   graph conv y1 -> xgA[s2]
//   GEMM2: block2 (K=192) + BN/ReLU + residual; y2 -> yb slots 2..13
//   gc3:   graph conv y2 -> xgA[s3]
//   GEMM3: block3 (K=192, DIL=2) + BN/ReLU + residual + pool -> part
// __launch_bounds__(256,2): LDS caps at 2 WG/CU anyway; give the allocator
// the full 256-VGPR budget so the 96-VGPR B-fragment arrays stay resident
// (round-4 VGPR_Count=88 proved they were being rematerialized per tile).
// ---------------------------------------------------------------------------
__global__ __launch_bounds__(256, 2) void stgcn_fused_kernel(
    const float* __restrict__ x, const float* __restrict__ adj,
    const short* __restrict__ effT0, const short* __restrict__ effT12,
    const float* __restrict__ bnc, float* __restrict__ part)
{
    __shared__ float adj_s[289];
    __shared__ __align__(16) float xt[16 * 51];         // 3264 B
    __shared__ __align__(16) short yb[16 * 17 * 72];    // 39168 B
    __shared__ __align__(16) short xgA[14 * 17 * 72];   // 34272 B
    __shared__ float pr[4][64];

    short* xg1st = xgA;   // alias: rows [238][40], dead after GEMM1

    const int tid = threadIdx.x;
    const int b = blockIdx.y;
    const int t0 = blockIdx.x * TT;

    const int lane = tid & 63;
    const int wave = tid >> 6;
    const int col = lane & 15;
    const int kgrp = lane >> 4;

    for (int i = tid; i < 289; i += 256) adj_s[i] = adj[i];

    // coalesced x-tile load: t in [t0-4, t0+12), 51 floats per t, zero-fill OOB
    {
        const int tbase = t0 - 4;
        const float* xb = x + (size_t)(b * T_DIM + tbase) * 51;
        for (int i = tid; i < 816; i += 256) {
            int tt = tbase + i / 51;
            float v = 0.f;
            if (tt >= 0 && tt < T_DIM) v = xb[i];
            xt[i] = v;
        }
    }

    // B-fragments for GEMM1 (K=32): global, independent of LDS
    s16x8 bf1[4];
    #pragma unroll
    for (int nt = 0; nt < 4; nt++)
        bf1[nt] = *(const s16x8*)(effT0 + (nt * 16 + col) * 32 + kgrp * 8);

    __syncthreads();

    // ---- phase A': per-row gc1 from LDS x-tile, K=32 A-layout pack ----
    if (tid < 238) {
        int s2 = tid / 17, j = tid - s2 * 17;
        float a9[9];
        #pragma unroll
        for (int q = 0; q < 9; q++) a9[q] = 0.f;
        int p0 = d_NBR_PTR[j], p1 = d_NBR_PTR[j + 1];
        for (int e = p0; e < p1; e++) {
            int k = d_NBR_K[e];
            float w = adj_s[k * 17 + j];
            #pragma unroll
            for (int dt = 0; dt < 3; dt++) {
                const float* xp = &xt[(s2 + dt) * 51 + k * 3];
                a9[dt * 3 + 0] += w * xp[0];
                a9[dt * 3 + 1] += w * xp[1];
                a9[dt * 3 + 2] += w * xp[2];
            }
        }
        __align__(16) unsigned ov[16];
        #pragma unroll
        for (int q = 0; q < 16; q++) ov[q] = 0u;
        #pragma unroll
        for (int dt = 0; dt < 3; dt++) {
            ov[dt * 4 + 0] = pk2bf(a9[dt * 3 + 0], a9[dt * 3 + 1]);
            ov[dt * 4 + 1] = pk2bf(a9[dt * 3 + 2], 0.f);
        }
        #pragma unroll
        for (int q = 0; q < 4; q++)
            *(int4*)&xg1st[tid * 40 + q * 8] = ((const int4*)ov)[q];
    }
    __syncthreads();

    // ---- GEMM1: block1, M=238 (14 t x 17 j), K=32, N=64 ----
    {
        float inv1[4], sh1[4];
        #pragma unroll
        for (int nt = 0; nt < 4; nt++) {
            inv1[nt] = bnc[nt * 16 + col];
            sh1[nt]  = bnc[192 + nt * 16 + col];
        }
        for (int tile = wave; tile < 15; tile += 4) {
            int m = tile * 16 + col;
            int me = m < 237 ? m : 237;
            s16x8 a = *(const s16x8*)&xg1st[me * 40 + kgrp * 8];
            f32x4 acc[4];
            #pragma unroll
            for (int nt = 0; nt < 4; nt++)
                acc[nt] = __builtin_amdgcn_mfma_f32_16x16x32_bf16(
                    a, bf1[nt], (f32x4){0.f, 0.f, 0.f, 0.f}, 0, 0, 0);
            int rl0 = tile * 16 + kgrp * 4;
            int sE = rl0 / 17, vE = rl0 - sE * 17;
            #pragma unroll
            for (int reg = 0; reg < 4; reg++) {
                int m2 = rl0 + reg;
                if (m2 < 238) {
                    int t = t0 - 3 + sE;
                    bool valid = (t >= 0) && (t < T_DIM);
                    #pragma unroll
                    for (int nt = 0; nt < 4; nt++) {
                        float val = valid
                            ? fmaxf(acc[nt][reg] * inv1[nt] + sh1[nt], 0.f) : 0.f;
                        yb[((sE + 1) * 17 + vE) * 72 + nt * 16 + col] = f2bf_fast(val);
                    }
                }
                vE++; if (vE == 17) { vE = 0; sE++; }
            }
        }
    }

    // B-fragments for GEMM2: issue loads here (before barrier) to overlap
    s16x8 bf2[6][4];
    #pragma unroll
    for (int kk = 0; kk < 6; kk++)
        #pragma unroll
        for (int nt = 0; nt < 4; nt++)
            bf2[kk][nt] = *(const s16x8*)(effT12 +
                (nt * 16 + col) * 192 + kk * 32 + kgrp * 8);

    __syncthreads();

    // ---- gc2: y1 -> xg2 ----
    for (int it = tid; it < 14 * 32; it += 256) {
        int s2 = it >> 5, cp = it & 31;
        float y0[17], y1r[17];
        #pragma unroll
        for (int k = 0; k < 17; k++) {
            short2 u = *(const short2*)&yb[((s2 + 1) * 17 + k) * 72 + cp * 2];
            y0[k] = bf2f(u.x); y1r[k] = bf2f(u.y);
        }
        #pragma unroll
        for (int v = 0; v < 17; v++) {
            float g0 = 0.f, g1 = 0.f;
            #pragma unroll
            for (int e = NBR_PTR[v]; e < NBR_PTR[v + 1]; e++) {
                int k = NBR_K[e];
                float w = adj_s[k * 17 + v];
                g0 += w * y0[k]; g1 += w * y1r[k];
            }
            *(unsigned*)&xgA[(s2 * 17 + v) * 72 + cp * 2] = pk2bf(g0, g1);
        }
    }
    __syncthreads();

    // ---- GEMM2: block2, M=204 (12 t x 17 v), K=192, DIL=1 ----
    {
        float inv2[4], sh2[4];
        #pragma unroll
        for (int nt = 0; nt < 4; nt++) {
            inv2[nt] = bnc[64 + nt * 16 + col];
            sh2[nt]  = bnc[256 + nt * 16 + col];
        }
        for (int tile = wave; tile < 13; tile += 4) {
            int m = tile * 16 + col;
            int me = m < 203 ? m : 203;
            int s3 = me / 17, v = me - s3 * 17;
            f32x4 acc[4];
            #pragma unroll
            for (int nt = 0; nt < 4; nt++) acc[nt] = (f32x4){0.f, 0.f, 0.f, 0.f};
            #pragma unroll
            for (int kk = 0; kk < 6; kk++) {
                int s = s3 + (kk >> 1);
                int c0 = (kk & 1) * 32 + kgrp * 8;
                s16x8 a = *(const s16x8*)&xgA[(s * 17 + v) * 72 + c0];
                #pragma unroll
                for (int nt = 0; nt < 4; nt++)
                    acc[nt] = __builtin_amdgcn_mfma_f32_16x16x32_bf16(
                        a, bf2[kk][nt], acc[nt], 0, 0, 0);
            }
            int rl0 = tile * 16 + kgrp * 4;
            int sE = rl0 / 17, vE = rl0 - sE * 17;
            #pragma unroll
            for (int reg = 0; reg < 4; reg++) {
                int m2 = rl0 + reg;
                if (m2 < 204) {
                    int t = t0 - 2 + sE;
                    bool valid = (t >= 0) && (t < T_DIM);
                    #pragma unroll
                    for (int nt = 0; nt < 4; nt++) {
                        int idx = ((sE + 2) * 17 + vE) * 72 + nt * 16 + col;
                        float res = bf2f(yb[idx]);
                        float val = valid
                            ? fmaxf(acc[nt][reg] * inv2[nt] + sh2[nt], 0.f) + res
                            : 0.f;
                        yb[idx] = f2bf_fast(val);   // y2 overwrites y1 (same thread)
                    }
                }
                vE++; if (vE == 17) { vE = 0; sE++; }
            }
        }
    }

    // B-fragments for GEMM3: issue before barrier
    s16x8 bf3[6][4];
    #pragma unroll
    for (int kk = 0; kk < 6; kk++)
        #pragma unroll
        for (int nt = 0; nt < 4; nt++)
            bf3[kk][nt] = *(const s16x8*)(effT12 + 12288 +
                (nt * 16 + col) * 192 + kk * 32 + kgrp * 8);

    __syncthreads();

    // ---- gc3: y2 -> xg3 ----
    for (int it = tid; it < 12 * 32; it += 256) {
        int s3 = it >> 5, cp = it & 31;
        float y0[17], y1r[17];
        #pragma unroll
        for (int k = 0; k < 17; k++) {
            short2 u = *(const short2*)&yb[((s3 + 2) * 17 + k) * 72 + cp * 2];
            y0[k] = bf2f(u.x); y1r[k] = bf2f(u.y);
        }
        #pragma unroll
        for (int v = 0; v < 17; v++) {
            float g0 = 0.f, g1 = 0.f;
            #pragma unroll
            for (int e = NBR_PTR[v]; e < NBR_PTR[v + 1]; e++) {
                int k = NBR_K[e];
                float w = adj_s[k * 17 + v];
                g0 += w * y0[k]; g1 += w * y1r[k];
            }
            *(unsigned*)&xgA[(s3 * 17 + v) * 72 + cp * 2] = pk2bf(g0, g1);
        }
    }
    __syncthreads();

    // ---- GEMM3: block3, M=136 (8 t x 17 v), K=192, DIL=2, + pool ----
    float psum[4] = {0.f, 0.f, 0.f, 0.f};
    {
        float inv3[4], sh3[4];
        #pragma unroll
        for (int nt = 0; nt < 4; nt++) {
            inv3[nt] = bnc[128 + nt * 16 + col];
            sh3[nt]  = bnc[320 + nt * 16 + col];
        }
        for (int tile = wave; tile < 9; tile += 4) {
            int m = tile * 16 + col;
            int me = m < 135 ? m : 135;
            int s4 = me / 17, v = me - s4 * 17;
            f32x4 acc[4];
            #pragma unroll
            for (int nt = 0; nt < 4; nt++) acc[nt] = (f32x4){0.f, 0.f, 0.f, 0.f};
            #pragma unroll
            for (int kk = 0; kk < 6; kk++) {
                int s = s4 + (kk >> 1) * 2;        // DIL=2
                int c0 = (kk & 1) * 32 + kgrp * 8;
                s16x8 a = *(const s16x8*)&xgA[(s * 17 + v) * 72 + c0];
                #pragma unroll
                for (int nt = 0; nt < 4; nt++)
                    acc[nt] = __builtin_amdgcn_mfma_f32_16x16x32_bf16(
                        a, bf3[kk][nt], acc[nt], 0, 0, 0);
            }
            int rl0 = tile * 16 + kgrp * 4;
            int sE = rl0 / 17, vE = rl0 - sE * 17;
            #pragma unroll
            for (int reg = 0; reg < 4; reg++) {
                int m2 = rl0 + reg;
                if (m2 < 136) {
                    #pragma unroll
                    for (int nt = 0; nt < 4; nt++) {
                        float res = bf2f(yb[((sE + 4) * 17 + vE) * 72 + nt * 16 + col]);
                        psum[nt] += fmaxf(acc[nt][reg] * inv3[nt] + sh3[nt], 0.f) + res;
                    }
                }
                vE++; if (vE == 17) { vE = 0; sE++; }
            }
        }
    }
    // pool reduce
    #pragma unroll
    for (int nt = 0; nt < 4; nt++) {
        float vv = psum[nt];
        vv += __shfl_xor(vv, 16);
        vv += __shfl_xor(vv, 32);
        if (lane < 16) pr[wave][nt * 16 + lane] = vv;
    }
    __syncthreads();
    if (tid < 64)
        part[((size_t)b * 256 + blockIdx.x) * 64 + tid] =
            pr[0][tid] + pr[1][tid] + pr[2][tid] + pr[3][tid];
}

// ---------------------------------------------------------------------------
// Sum 256 partials per (b,c), mean, LayerNorm, FC. 1 wave per b.
// ---------------------------------------------------------------------------
__global__ __launch_bounds__(64) void finish_kernel(
    const float* __restrict__ part, const float* __restrict__ ln_s,
    const float* __restrict__ ln_b, const float* __restrict__ fc_w,
    const float* __restrict__ fc_b, float* __restrict__ out)
{
    const int b = blockIdx.x;
    const int c = threadIdx.x;
    float s = 0.f;
    for (int i = 0; i < 256; i++)
        s += part[((size_t)b * 256 + i) * 64 + c];
    float feat = s / (float)(T_DIM * K_DIM);

    float m = feat;
    #pragma unroll
    for (int off = 32; off > 0; off >>= 1) m += __shfl_down(m, off);
    m = __shfl(m, 0) / 64.f;
    float d = feat - m;
    float v = d * d;
    #pragma unroll
    for (int off = 32; off > 0; off >>= 1) v += __shfl_down(v, off);
    v = __shfl(v, 0) / 64.f;
    float norm = d * rsqrtf(v + 1e-5f) * ln_s[c] + ln_b[c];

    __shared__ float ns[64];
    ns[c] = norm;
    __syncthreads();
    if (c < 10) {
        float o = fc_b[c];
        for (int i = 0; i < 64; i++) o += ns[i] * fc_w[i * 10 + c];
        out[b * 10 + c] = o;
    }
}

// ---------------------------------------------------------------------------
extern "C" void kernel_launch(void* const* d_in, const int* in_sizes, int n_in,
                              void* d_out, int out_size, void* d_ws, size_t ws_size,
                              hipStream_t stream)
{
    const float* kpts = (const float*)d_in[0];
    const float* adj  = (const float*)d_in[1];
    const float* gw0  = (const float*)d_in[2];
    const float* gw1  = (const float*)d_in[3];
    const float* gw2  = (const float*)d_in[4];
    const float* tcn  = (const float*)d_in[5];
    const float* bns  = (const float*)d_in[6];
    const float* bnb  = (const float*)d_in[7];
    const float* bnm  = (const float*)d_in[8];
    const float* bnv  = (const float*)d_in[9];
    const float* lns  = (const float*)d_in[10];
    const float* lnb  = (const float*)d_in[11];
    const float* fcw  = (const float*)d_in[12];
    const float* fcb  = (const float*)d_in[13];
    float* out = (float*)d_out;

    // workspace: bnc(384 f) | part(32*256*64 f) | effT0(2048 bf16) | effT12(24576 bf16)
    float* bnc  = (float*)d_ws;
    float* part = bnc + 384;
    short* effT0  = (short*)(part + (size_t)B_DIM * 256 * 64);
    short* effT12 = effT0 + 2048;
    // total ~2.15 MB — activations never leave LDS

    fold_weights_kernel<<<64, 256, 0, stream>>>(gw0, gw1, gw2, tcn,
                                                bns, bnb, bnm, bnv,
                                                effT0, effT12, bnc);

    stgcn_fused_kernel<<<dim3(T_DIM / TT, B_DIM), 256, 0, stream>>>(
        kpts, adj, effT0, effT12, bnc, part);

    finish_kernel<<<B_DIM, 64, 0, stream>>>(part, lns, lnb, fcw, fcb, out);
}